// Round 11
// baseline (139.009 us; speedup 1.0000x reference)
//
#include <hip/hip_runtime.h>

typedef __attribute__((ext_vector_type(8))) short bf16x8;
typedef __attribute__((ext_vector_type(4))) float f32x4;
typedef __attribute__((ext_vector_type(16))) float f32x16;
typedef __attribute__((ext_vector_type(2))) unsigned short u16x2;
typedef __attribute__((ext_vector_type(4))) unsigned short u16x4;
typedef __attribute__((ext_vector_type(2))) unsigned int u32x2;

static constexpr int kB = 2;
static constexpr int kT = 2048;
static constexpr int kC = 1024;
static constexpr int kH = 16;
static constexpr int kD = 64;
static constexpr int kNC = 16;  // chunks of 128

__device__ inline unsigned short f2bf(float f) {
    unsigned int u = __float_as_uint(f);
    u += 0x7FFFu + ((u >> 16) & 1u);
    return (unsigned short)(u >> 16);
}
__device__ inline float bf2f(unsigned short u) {
    return __uint_as_float(((unsigned int)u) << 16);
}

#define GLDS16(g, s)                                                            \
    __builtin_amdgcn_global_load_lds(                                           \
        (const __attribute__((address_space(1))) unsigned int*)(g),             \
        (__attribute__((address_space(3))) unsigned int*)(s), 16, 0, 0)

// ---------------- f32 -> bf16 convert ----------------
__global__ __launch_bounds__(256) void cvt_bf16(const float* __restrict__ in,
                                                unsigned short* __restrict__ out, int n) {
    int i = (blockIdx.x * 256 + threadIdx.x) * 4;
    if (i >= n) return;
    float4 v = *(const float4*)(in + i);
    u16x4 o;
    o[0] = f2bf(v.x); o[1] = f2bf(v.y); o[2] = f2bf(v.z); o[3] = f2bf(v.w);
    *(u16x4*)(out + i) = o;
}

// ---------------- RoPE tables + decay LUTs in one launch ----------------
__global__ __launch_bounds__(256) void make_tables(float2* __restrict__ qtab,
                                                   float2* __restrict__ ktab,
                                                   float* __restrict__ decq,
                                                   float* __restrict__ deck) {
    int idx = blockIdx.x * 256 + threadIdx.x;
    if (idx < kT * 32) {
        int t = idx >> 5, i = idx & 31;
        float half = 2.0f * (float)i;
        float inv_freq = powf(10000.0f, -half / 64.0f);
        float fr = (float)t * inv_freq;
        float sv = (half + 0.4f * 64.0f) / (1.4f * 64.0f);
        float p = ((float)t - 1024.0f) / 512.0f;
        float scl = powf(sv, p);
        float c = cosf(fr), s = sinf(fr);
        qtab[idx] = make_float2(c * scl, s * scl);
        ktab[idx] = make_float2(c / scl, s / scl);
    }
    if (idx < kH * 128) {
        int h = idx >> 7, tt = idx & 127;
        float log2g = log2f(1.0f - exp2f(-5.0f - (float)h));
        decq[idx] = 0.125f * exp2f(log2g * (float)tt);
        deck[idx] = exp2f(-log2g * (float)tt);
    }
}

// ---------------- mega input GEMM: C = xb @ [wq;wk;wv;wg]^T (M4096,N4096,K1024) --
// tile 128x128, 4 waves, single-buffer (r9-proven). LIGHT epilogues:
// q/k -> plain bf16 rows (u32-packed); v -> transposed vtb; gated -> silu gbuf.
__global__ __launch_bounds__(256) void gemm_qkvg(const unsigned short* __restrict__ A,
                                                 const unsigned short* __restrict__ Bm,
                                                 unsigned short* __restrict__ qb,
                                                 unsigned short* __restrict__ kbuf,
                                                 unsigned short* __restrict__ vtb,
                                                 unsigned short* __restrict__ gbuf) {
    constexpr int K = 1024;
    __shared__ __align__(16) unsigned short Al[128 * 64];
    __shared__ __align__(16) unsigned short Bl[128 * 64];
    char* ab = (char*)Al;
    char* bb = (char*)Bl;
    const int tid = threadIdx.x;
    const int l = tid & 63, w = tid >> 6;
    const int wr = w >> 1, wc = w & 1;
    const int tm = blockIdx.y * 128, tn = blockIdx.x * 128;
    const int ri = l >> 3;
    const int su = (l & 7) ^ (ri & 7);

    f32x4 zero4 = {0.0f, 0.0f, 0.0f, 0.0f};
    f32x4 acc[4][4];
#pragma unroll
    for (int m = 0; m < 4; m++)
#pragma unroll
        for (int n = 0; n < 4; n++) acc[m][n] = zero4;

    for (int kt = 0; kt < K; kt += 64) {
#pragma unroll
        for (int c = w; c < 32; c += 4) {
            if (c < 16) {
                const unsigned short* src = A + (size_t)(tm + c * 8 + ri) * K + kt + su * 8;
                GLDS16(src, ab + c * 1024);
            } else {
                int cb = c - 16;
                const unsigned short* src = Bm + (size_t)(tn + cb * 8 + ri) * K + kt + su * 8;
                GLDS16(src, bb + cb * 1024);
            }
        }
        __syncthreads();
#pragma unroll
        for (int ks = 0; ks < 2; ks++) {
            bf16x8 af[4], bfr[4];
            int kbyte = ks * 64 + (l >> 4) * 16;
#pragma unroll
            for (int m = 0; m < 4; m++) {
                int row = wr * 64 + m * 16 + (l & 15);
                af[m] = *(const bf16x8*)(ab + row * 128 + (kbyte ^ ((row & 7) << 4)));
            }
#pragma unroll
            for (int n = 0; n < 4; n++) {
                int row = wc * 64 + n * 16 + (l & 15);
                bfr[n] = *(const bf16x8*)(bb + row * 128 + (kbyte ^ ((row & 7) << 4)));
            }
#pragma unroll
            for (int m = 0; m < 4; m++)
#pragma unroll
                for (int n = 0; n < 4; n++)
                    acc[m][n] = __builtin_amdgcn_mfma_f32_16x16x32_bf16(af[m], bfr[n], acc[m][n], 0, 0, 0);
        }
        __syncthreads();
    }

    if (tn < 2048) {
        // q or k: plain bf16 (B,H,T,D) rows, u32-packed pair stores
        const bool isq = (tn < 1024);
        unsigned short* dst = isq ? qb : kbuf;
        const int colbase = isq ? tn : (tn - 1024);
#pragma unroll
        for (int n = 0; n < 4; n++) {
            int col = colbase + wc * 64 + n * 16 + (l & 15);
            int h = col >> 6;
            int d = col & 63;
#pragma unroll
            for (int m = 0; m < 4; m++) {
#pragma unroll
                for (int r = 0; r < 4; r++) {
                    int row = tm + wr * 64 + m * 16 + (l >> 4) * 4 + r;
                    int b = row >> 11, t = row & 2047;
                    unsigned int ub = f2bf(acc[m][n][r]);
                    unsigned int pb = (unsigned int)__shfl_xor((int)ub, 1);
                    if (!(l & 1)) {
                        unsigned int packed = (ub & 0xFFFFu) | (pb << 16);
                        *(unsigned int*)(dst + ((size_t)(b * 16 + h) * 2048 + t) * 64 + d) = packed;
                    }
                }
            }
        }
    } else if (tn < 3072) {
        // v: transposed bf16 write (B, Cv, T), u16x4 = 4 consecutive t
#pragma unroll
        for (int m = 0; m < 4; m++)
#pragma unroll
            for (int n = 0; n < 4; n++) {
                int col2 = (tn - 2048) + wc * 64 + n * 16 + (l & 15);
                int rowb = tm + wr * 64 + m * 16 + (l >> 4) * 4;
                int b = rowb >> 11, t = rowb & 2047;
                u16x4 o;
#pragma unroll
                for (int r = 0; r < 4; r++) o[r] = f2bf(acc[m][n][r]);
                *(u16x4*)(vtb + ((size_t)(b * 1024 + col2)) * 2048 + t) = o;
            }
    } else {
        // gated: silu -> bf16, u32-packed pair stores
#pragma unroll
        for (int n = 0; n < 4; n++) {
            int col3 = (tn - 3072) + wc * 64 + n * 16 + (l & 15);
#pragma unroll
            for (int m = 0; m < 4; m++) {
#pragma unroll
                for (int r = 0; r < 4; r++) {
                    int row = tm + wr * 64 + m * 16 + (l >> 4) * 4 + r;
                    float v = acc[m][n][r];
                    float sv2 = v / (1.0f + expf(-v));
                    unsigned int ub = f2bf(sv2);
                    unsigned int pb = (unsigned int)__shfl_xor((int)ub, 1);
                    if (!(l & 1)) {
                        unsigned int packed = (ub & 0xFFFFu) | (pb << 16);
                        *(unsigned int*)(gbuf + (size_t)row * 1024 + col3) = packed;
                    }
                }
            }
        }
    }
}

// ---------------- rope_qkt: in-place RoPE+decay on qb,kbuf rows; also emit K^T ----
__global__ __launch_bounds__(256) void rope_qkt(unsigned short* __restrict__ qb,
                                                unsigned short* __restrict__ kbuf,
                                                unsigned short* __restrict__ ktb,
                                                const float2* __restrict__ qtab,
                                                const float2* __restrict__ ktab,
                                                const float* __restrict__ decq,
                                                const float* __restrict__ deck) {
    __shared__ unsigned short tile[64][72];
    const int bh = blockIdx.x;
    const int tt = blockIdx.y * 64;
    const int h = bh & 15;
    const int tl = threadIdx.x >> 2;
    const int du = (threadIdx.x & 3) * 16;
    const int t = tt + tl;
    const float dq = decq[h * 128 + (t & 127)];
    const float dk = deck[h * 128 + (t & 127)];

    {
        unsigned short* qrow = qb + ((size_t)bh * kT + t) * kD + du;
        bf16x8 a0 = *(const bf16x8*)(qrow);
        bf16x8 a1 = *(const bf16x8*)(qrow + 8);
        bf16x8 o0, o1;
#pragma unroll
        for (int j = 0; j < 4; ++j) {
            float2 cs = qtab[t * 32 + (du >> 1) + j];
            float x0 = bf2f((unsigned short)a0[2 * j]);
            float x1 = bf2f((unsigned short)a0[2 * j + 1]);
            o0[2 * j] = (short)f2bf((x0 * cs.x - x1 * cs.y) * dq);
            o0[2 * j + 1] = (short)f2bf((x1 * cs.x + x0 * cs.y) * dq);
            float2 cs2 = qtab[t * 32 + (du >> 1) + 4 + j];
            float y0 = bf2f((unsigned short)a1[2 * j]);
            float y1 = bf2f((unsigned short)a1[2 * j + 1]);
            o1[2 * j] = (short)f2bf((y0 * cs2.x - y1 * cs2.y) * dq);
            o1[2 * j + 1] = (short)f2bf((y1 * cs2.x + y0 * cs2.y) * dq);
        }
        *(bf16x8*)(qrow) = o0;
        *(bf16x8*)(qrow + 8) = o1;
    }
    {
        unsigned short* krow = kbuf + ((size_t)bh * kT + t) * kD + du;
        bf16x8 a0 = *(const bf16x8*)(krow);
        bf16x8 a1 = *(const bf16x8*)(krow + 8);
        bf16x8 o0, o1;
#pragma unroll
        for (int j = 0; j < 4; ++j) {
            float2 cs = ktab[t * 32 + (du >> 1) + j];
            float x0 = bf2f((unsigned short)a0[2 * j]);
            float x1 = bf2f((unsigned short)a0[2 * j + 1]);
            o0[2 * j] = (short)f2bf((x0 * cs.x - x1 * cs.y) * dk);
            o0[2 * j + 1] = (short)f2bf((x1 * cs.x + x0 * cs.y) * dk);
            float2 cs2 = ktab[t * 32 + (du >> 1) + 4 + j];
            float y0 = bf2f((unsigned short)a1[2 * j]);
            float y1 = bf2f((unsigned short)a1[2 * j + 1]);
            o1[2 * j] = (short)f2bf((y0 * cs2.x - y1 * cs2.y) * dk);
            o1[2 * j + 1] = (short)f2bf((y1 * cs2.x + y0 * cs2.y) * dk);
        }
        *(bf16x8*)(krow) = o0;
        *(bf16x8*)(krow + 8) = o1;
#pragma unroll
        for (int e = 0; e < 8; ++e) {
            tile[tl][du + e] = (unsigned short)o0[e];
            tile[tl][du + 8 + e] = (unsigned short)o1[e];
        }
    }
    __syncthreads();
    {
        int dd = threadIdx.x >> 2;
        int tb2 = (threadIdx.x & 3) * 16;
        bf16x8 o0, o1;
#pragma unroll
        for (int e = 0; e < 8; ++e) {
            o0[e] = (short)tile[tb2 + e][dd];
            o1[e] = (short)tile[tb2 + 8 + e][dd];
        }
        unsigned short* drow = ktb + ((size_t)bh * kD + dd) * kT + tt + tb2;
        *(bf16x8*)(drow) = o0;
        *(bf16x8*)(drow + 8) = o1;
    }
}

// ---------------- chunk_m: Mt[bh][c] = g^128 * (V_c^T K~_c) as M^T[d2][d1], bf16 ----
__global__ __launch_bounds__(256) void chunk_m(const unsigned short* __restrict__ ktb,
                                               const unsigned short* __restrict__ vtb,
                                               unsigned short* __restrict__ Mt) {
    __shared__ __align__(16) unsigned short Ktl[64 * 128];
    __shared__ __align__(16) unsigned short Vtl[64 * 128];
    const int tid = threadIdx.x, l = tid & 63, w = tid >> 6;
    const int bh = blockIdx.x, c = blockIdx.y, h = bh & 15;
    const int ql = l & 31, hi5 = l >> 5;
    char* kp = (char*)Ktl;
    char* vp = (char*)Vtl;
#pragma unroll
    for (int j = 0; j < 4; ++j) {
        int ch = w * 4 + j;
        int row = ch * 4 + (l >> 4);
        int u = (l & 15) ^ (row & 15);
        GLDS16(ktb + ((size_t)bh * kD + row) * kT + c * 128 + u * 8, kp + ch * 1024);
        GLDS16(vtb + ((size_t)bh * kD + row) * kT + c * 128 + u * 8, vp + ch * 1024);
    }
    __syncthreads();
    const int iw = w >> 1, jw = w & 1;
    f32x16 acc;
#pragma unroll
    for (int r = 0; r < 16; ++r) acc[r] = 0.0f;
#pragma unroll
    for (int sk = 0; sk < 8; ++sk) {
        int rowa = iw * 32 + ql;
        int rowb = jw * 32 + ql;
        bf16x8 av = *(const bf16x8*)(vp + rowa * 256 + 16 * ((2 * sk + hi5) ^ (rowa & 15)));
        bf16x8 bk = *(const bf16x8*)(kp + rowb * 256 + 16 * ((2 * sk + hi5) ^ (rowb & 15)));
        acc = __builtin_amdgcn_mfma_f32_32x32x16_bf16(av, bk, acc, 0, 0, 0);
    }
    float log2g = log2f(1.0f - exp2f(-5.0f - (float)h));
    float gC = exp2f(128.0f * log2g);
    unsigned short* mo = Mt + ((size_t)(bh * kNC + c)) * 4096;
#pragma unroll
    for (int r = 0; r < 16; ++r) {
        int row = iw * 32 + (r & 3) + 8 * (r >> 2) + 4 * hi5;
        int col = jw * 32 + ql;
        mo[row * 64 + col] = f2bf(acc[r] * gC);
    }
}

// ---------------- chunk_states (serial Horner per bh, 32 blocks) ----------------
// St[bh][c] = gC*St[bh][c-1] + Mt[bh][c-1], St[bh][0] = 0. One pass over Mt.
__global__ __launch_bounds__(256) void chunk_states(const unsigned short* __restrict__ Mt,
                                                    unsigned short* __restrict__ St) {
    const int bh = blockIdx.x, h = bh & 15;
    const int tid = threadIdx.x;
    float log2g = log2f(1.0f - exp2f(-5.0f - (float)h));
    float gC = exp2f(128.0f * log2g);
    float state[16];
#pragma unroll
    for (int e = 0; e < 16; ++e) state[e] = 0.0f;
    for (int c = 0; c < kNC; ++c) {
        unsigned short* so = St + ((size_t)(bh * kNC + c)) * 4096;
        const unsigned short* m = Mt + ((size_t)(bh * kNC + c)) * 4096;
#pragma unroll
        for (int k = 0; k < 4; ++k) {
            u16x4 o;
#pragma unroll
            for (int e = 0; e < 4; ++e) o[e] = f2bf(state[k * 4 + e]);
            *(u16x4*)(so + (k * 256 + tid) * 4) = o;
            u16x4 v = *(const u16x4*)(m + (k * 256 + tid) * 4);
#pragma unroll
            for (int e = 0; e < 4; ++e)
                state[k * 4 + e] = state[k * 4 + e] * gC + bf2f(v[e]);
        }
    }
}

// ---------------- chunk_attn: y_c = mask(Q~K~^T) V + Q~ S_c (y bf16) + GN partial --
__global__ __launch_bounds__(512) void chunk_attn(const unsigned short* __restrict__ qb,
                                                  const unsigned short* __restrict__ kb,
                                                  const unsigned short* __restrict__ vtb,
                                                  const unsigned short* __restrict__ St,
                                                  unsigned short* __restrict__ yb,
                                                  float* __restrict__ part) {
    __shared__ __align__(16) unsigned short Kt[128 * 64];
    __shared__ __align__(16) unsigned short Vt[64 * 128];
    __shared__ __align__(16) unsigned short Ss[64 * 64];
    __shared__ __align__(16) unsigned short Pl[8 * 32 * 64];
    __shared__ float red[16];
    const int tid = threadIdx.x, l = tid & 63, w = tid >> 6;
    const int bh = blockIdx.x, c = blockIdx.y;
    const int qw = w >> 1, dw = w & 1;
    const int ql = l & 31, hi5 = l >> 5;
    char* kp = (char*)Kt;
    char* vp = (char*)Vt;
    char* sp = (char*)Ss;
    char* pw = (char*)Pl + w * 4096;

#pragma unroll
    for (int j = 0; j < 2; ++j) {
        int ch = w * 2 + j;
        int row = ch * 8 + (l >> 3);
        int u = (l & 7) ^ (row & 7);
        GLDS16(kb + ((size_t)bh * kT + c * 128 + row) * kD + u * 8, kp + ch * 1024);
    }
#pragma unroll
    for (int j = 0; j < 2; ++j) {
        int ch = w * 2 + j;
        int row = ch * 4 + (l >> 4);
        int u = (l & 15) ^ (row & 15);
        GLDS16(vtb + ((size_t)bh * kD + row) * kT + c * 128 + u * 8, vp + ch * 1024);
    }
    {
        int row = w * 8 + (l >> 3);
        int u = (l & 7) ^ (row & 7);
        GLDS16(St + ((size_t)(bh * kNC + c)) * 4096 + row * 64 + u * 8, sp + w * 1024);
    }
    bf16x8 aq[4];
    {
        const unsigned short* qrow = qb + ((size_t)bh * kT + c * 128 + qw * 32 + ql) * kD + hi5 * 8;
#pragma unroll
        for (int dk = 0; dk < 4; ++dk) aq[dk] = *(const bf16x8*)(qrow + dk * 16);
    }
    __syncthreads();

    f32x16 acc;
#pragma unroll
    for (int r = 0; r < 16; ++r) acc[r] = 0.0f;
    const int qidx = qw * 32 + ql;

#pragma unroll
    for (int p = 0; p < 2; ++p) {
        f32x16 sA, sB;
#pragma unroll
        for (int r = 0; r < 16; ++r) { sA[r] = 0.0f; sB[r] = 0.0f; }
#pragma unroll
        for (int dk = 0; dk < 4; ++dk) {
            int rowa = (2 * p) * 32 + ql;
            int rowb = (2 * p + 1) * 32 + ql;
            bf16x8 ka = *(const bf16x8*)(kp + rowa * 128 + 16 * ((2 * dk + hi5) ^ (rowa & 7)));
            bf16x8 kb2 = *(const bf16x8*)(kp + rowb * 128 + 16 * ((2 * dk + hi5) ^ (rowb & 7)));
            sA = __builtin_amdgcn_mfma_f32_32x32x16_bf16(ka, aq[dk], sA, 0, 0, 0);
            sB = __builtin_amdgcn_mfma_f32_32x32x16_bf16(kb2, aq[dk], sB, 0, 0, 0);
        }
#pragma unroll
        for (int sb2 = 0; sb2 < 2; ++sb2) {
            int sbase = (2 * p + sb2) * 32 + 4 * hi5;
#pragma unroll
            for (int m = 0; m < 4; ++m) {
                float v0, v1, v2, v3;
                {
                    int s0i = sbase + 8 * m;
                    float x0 = sb2 ? sB[4 * m + 0] : sA[4 * m + 0];
                    float x1 = sb2 ? sB[4 * m + 1] : sA[4 * m + 1];
                    float x2 = sb2 ? sB[4 * m + 2] : sA[4 * m + 2];
                    float x3 = sb2 ? sB[4 * m + 3] : sA[4 * m + 3];
                    v0 = (qidx >= s0i + 0) ? x0 : 0.0f;
                    v1 = (qidx >= s0i + 1) ? x1 : 0.0f;
                    v2 = (qidx >= s0i + 2) ? x2 : 0.0f;
                    v3 = (qidx >= s0i + 3) ? x3 : 0.0f;
                }
                unsigned int lo, hi;
                asm("v_cvt_pk_bf16_f32 %0, %1, %2" : "=v"(lo) : "v"(v0), "v"(v1));
                asm("v_cvt_pk_bf16_f32 %0, %1, %2" : "=v"(hi) : "v"(v2), "v"(v3));
                u32x2 pr; pr[0] = lo; pr[1] = hi;
                *(u32x2*)(pw + ql * 128 + (((sb2 * 4 + m) * 16) ^ ((ql & 7) << 4)) + hi5 * 8) = pr;
            }
        }
#pragma unroll
        for (int kki = 0; kki < 4; ++kki) {
            bf16x8 ap = *(const bf16x8*)(pw + ql * 128 + 16 * ((2 * kki + hi5) ^ (ql & 7)));
            int rowv = dw * 32 + ql;
            bf16x8 bv = *(const bf16x8*)(vp + rowv * 256 + 16 * ((2 * (4 * p + kki) + hi5) ^ (rowv & 15)));
            acc = __builtin_amdgcn_mfma_f32_32x32x16_bf16(ap, bv, acc, 0, 0, 0);
        }
    }
#pragma unroll
    for (int dk = 0; dk < 4; ++dk) {
        int rows = dw * 32 + ql;
        bf16x8 bs = *(const bf16x8*)(sp + rows * 128 + 16 * ((2 * dk + hi5) ^ (rows & 7)));
        acc = __builtin_amdgcn_mfma_f32_32x32x16_bf16(aq[dk], bs, acc, 0, 0, 0);
    }
    float s = 0.0f, s2 = 0.0f;
#pragma unroll
    for (int r = 0; r < 16; ++r) {
        int row = c * 128 + qw * 32 + (r & 3) + 8 * (r >> 2) + 4 * hi5;
        int col = dw * 32 + ql;
        unsigned short ub = f2bf(acc[r]);
        yb[((size_t)bh * kT + row) * kD + col] = ub;
        float f = bf2f(ub);
        s += f; s2 += f * f;
    }
#pragma unroll
    for (int o = 32; o > 0; o >>= 1) {
        s += __shfl_down(s, o);
        s2 += __shfl_down(s2, o);
    }
    if (l == 0) { red[w * 2] = s; red[w * 2 + 1] = s2; }
    __syncthreads();
    if (tid == 0) {
        float S = 0.0f, S2 = 0.0f;
#pragma unroll
        for (int i = 0; i < 8; i++) { S += red[2 * i]; S2 += red[2 * i + 1]; }
        part[((size_t)bh * kNC + c) * 2] = S;
        part[((size_t)bh * kNC + c) * 2 + 1] = S2;
    }
}

__global__ __launch_bounds__(64) void gn_fin(const float* __restrict__ part,
                                             float* __restrict__ stats) {
    int bh = threadIdx.x;
    if (bh >= kB * kH) return;
    float S = 0.0f, S2 = 0.0f;
#pragma unroll
    for (int i = 0; i < kNC; i++) {
        S += part[(bh * kNC + i) * 2];
        S2 += part[(bh * kNC + i) * 2 + 1];
    }
    const float inv = 1.0f / (float)(kT * kD);
    float mean = S * inv;
    float var = S2 * inv - mean * mean;
    stats[2 * bh] = mean;
    stats[2 * bh + 1] = rsqrtf(var + 1e-5f);
}

// ---------------- GEMM C[M,N] = A @ Bm^T, fp32 out (proj), single-buffer --------
__global__ __launch_bounds__(256) void gemm_proj(const unsigned short* __restrict__ A,
                                                 const unsigned short* __restrict__ Bm,
                                                 float* __restrict__ Cf,
                                                 int N, int K) {
    __shared__ __align__(16) unsigned short Al[128 * 64];
    __shared__ __align__(16) unsigned short Bl[128 * 64];
    char* ab = (char*)Al;
    char* bb = (char*)Bl;
    const int tid = threadIdx.x;
    const int l = tid & 63, w = tid >> 6;
    const int wr = w >> 1, wc = w & 1;
    const int tm = blockIdx.y * 128, tn = blockIdx.x * 128;
    const int ri = l >> 3;
    const int su = (l & 7) ^ (ri & 7);

    f32x4 zero4 = {0.0f, 0.0f, 0.0f, 0.0f};
    f32x4 acc[4][4];
#pragma unroll
    for (int m = 0; m < 4; m++)
#pragma unroll
        for (int n = 0; n < 4; n++) acc[m][n] = zero4;

    for (int kt = 0; kt < K; kt += 64) {
#pragma unroll
        for (int c = w; c < 32; c += 4) {
            if (c < 16) {
                const unsigned short* src = A + (size_t)(tm + c * 8 + ri) * K + kt + su * 8;
                GLDS16(src, ab + c * 1024);
            } else {
                int cb = c - 16;
                const unsigned short* src = Bm + (size_t)(tn + cb * 8 + ri) * K + kt + su * 8;
                GLDS16(src, bb + cb * 1024);
            }
        }
        __syncthreads();
#pragma unroll
        for (int ks = 0; ks < 2; ks++) {
            bf16x8 af[4], bfr[4];
            int kbyte = ks * 64 + (l >> 4) * 16;
#pragma unroll
            for (int m = 0; m < 4; m++) {
                int row = wr * 64 + m * 16 + (l & 15);
                af[m] = *(const bf16x8*)(ab + row * 128 + (kbyte ^ ((row & 7) << 4)));
            }
#pragma unroll
            for (int n = 0; n < 4; n++) {
                int row = wc * 64 + n * 16 + (l & 15);
                bfr[n] = *(const bf16x8*)(bb + row * 128 + (kbyte ^ ((row & 7) << 4)));
            }
#pragma unroll
            for (int m = 0; m < 4; m++)
#pragma unroll
                for (int n = 0; n < 4; n++)
                    acc[m][n] = __builtin_amdgcn_mfma_f32_16x16x32_bf16(af[m], bfr[n], acc[m][n], 0, 0, 0);
        }
        __syncthreads();
    }
#pragma unroll
    for (int m = 0; m < 4; m++)
#pragma unroll
        for (int n = 0; n < 4; n++)
#pragma unroll
            for (int r = 0; r < 4; r++) {
                int row = tm + wr * 64 + m * 16 + (l >> 4) * 4 + r;
                int col = tn + wc * 64 + n * 16 + (l & 15);
                Cf[(size_t)row * N + col] = acc[m][n][r];
            }
}

// ---------------- z = bf16( gsilu * ((y - mean)*rstd*gw + gb) ) ----------------
__global__ __launch_bounds__(256) void fuse_z(const unsigned short* __restrict__ gb,
                                              const unsigned short* __restrict__ yb,
                                              const float* __restrict__ stats,
                                              const float* __restrict__ gnw,
                                              const float* __restrict__ gnb,
                                              unsigned short* __restrict__ z) {
    int idx = blockIdx.x * 256 + threadIdx.x;  // (B*T*C)/4
    int row = idx >> 8;
    int c = (idx & 255) << 2;
    int b = row >> 11, t = row & 2047;
    int h = c >> 6, d = c & 63;
    int bh = b * kH + h;
    u16x4 gv = *(const u16x4*)(gb + (size_t)row * kC + c);
    u16x4 yv = *(const u16x4*)(yb + (((size_t)bh * kT) + t) * kD + d);
    float mean = stats[2 * bh], rstd = stats[2 * bh + 1];
    float4 wv = *(const float4*)(gnw + c);
    float4 bv = *(const float4*)(gnb + c);
    u16x4 o;
    o[0] = f2bf(bf2f(gv[0]) * ((bf2f(yv[0]) - mean) * rstd * wv.x + bv.x));
    o[1] = f2bf(bf2f(gv[1]) * ((bf2f(yv[1]) - mean) * rstd * wv.y + bv.y));
    o[2] = f2bf(bf2f(gv[2]) * ((bf2f(yv[2]) - mean) * rstd * wv.z + bv.z));
    o[3] = f2bf(bf2f(gv[3]) * ((bf2f(yv[3]) - mean) * rstd * wv.w + bv.w));
    *(u16x4*)(z + (size_t)row * kC + c) = o;
}

extern "C" void kernel_launch(void* const* d_in, const int* in_sizes, int n_in,
                              void* d_out, int out_size, void* d_ws, size_t ws_size,
                              hipStream_t stream) {
    const float* x = (const float*)d_in[0];
    const float* w_qkv = (const float*)d_in[1];
    const float* w_gated = (const float*)d_in[2];
    const float* w_proj = (const float*)d_in[3];
    const float* gnw = (const float*)d_in[4];
    const float* gnb = (const float*)d_in[5];
    float* out = (float*)d_out;
    char* ws = (char*)d_ws;

    unsigned short* xb      = (unsigned short*)(ws + 0);         // 8 MB
    unsigned short* wqkvb   = (unsigned short*)(ws + 8388608);   // 6 MB
    unsigned short* wgatedb = (unsigned short*)(ws + 14680064);  // 2 MB
    unsigned short* wprojb  = (unsigned short*)(ws + 16777216);  // 2 MB
    unsigned short* qb      = (unsigned short*)(ws + 18874368);  // 8 MB (B,H,T,D)
    unsigned short* kbuf    = (unsigned short*)(ws + 27262976);  // 8 MB (B,H,T,D)
    unsigned short* vtb     = (unsigned short*)(ws + 35651584);  // 8 MB (B,H,D,T)
    unsigned short* zb      = (unsigned short*)(ws + 44040192);  // 8 MB
    float* part  = (float*)(ws + 44040192);                      // 4 KB in zb (dead before fuse_z)
    float* stats = (float*)(ws + 52428800);                      // 256 B
    float2* qtab = (float2*)(ws + 52429056);                     // 512 KB
    float2* ktab = (float2*)(ws + 52953344);                     // 512 KB
    float*  decq = (float*)(ws + 53477632);                      // 8 KB
    float*  deck = (float*)(ws + 53485824);                      // 8 KB
    unsigned short* Mt  = (unsigned short*)(ws + 52429056);      // 4 MB (overlays tables)
    unsigned short* St  = (unsigned short*)(ws + 56623360);      // 4 MB
    unsigned short* yb  = (unsigned short*)(ws + 60817664);      // 8 MB
    unsigned short* gbuf= (unsigned short*)(ws + 69206272);      // 8 MB
    unsigned short* ktb = (unsigned short*)(ws + 77594880);      // 8 MB -> ends 85983232

    cvt_bf16<<<4096, 256, 0, stream>>>(x, xb, kB * kT * kC);
    cvt_bf16<<<3072, 256, 0, stream>>>(w_qkv, wqkvb, 3 * kC * kC);
    cvt_bf16<<<1024, 256, 0, stream>>>(w_gated, wgatedb, kC * kC);
    cvt_bf16<<<1024, 256, 0, stream>>>(w_proj, wprojb, kC * kC);
    make_tables<<<256, 256, 0, stream>>>(qtab, ktab, decq, deck);

    // mega GEMM: q->qb, k->kbuf (plain rows), v->vtb (transposed), gated->gbuf (silu)
    gemm_qkvg<<<dim3(32, 32), 256, 0, stream>>>(xb, wqkvb, qb, kbuf, vtb, gbuf);

    // in-place rope on qb/kbuf + emit K^T
    rope_qkt<<<dim3(kB * kH, kT / 64), 256, 0, stream>>>(qb, kbuf, ktb, qtab, ktab, decq, deck);

    // chunked retention (bh fastest -> XCD = bh%8)
    chunk_m<<<dim3(kB * kH, kNC), 256, 0, stream>>>(ktb, vtb, Mt);
    chunk_states<<<kB * kH, 256, 0, stream>>>(Mt, St);
    chunk_attn<<<dim3(kB * kH, kNC), 512, 0, stream>>>(qb, kbuf, vtb, St, yb, part);

    gn_fin<<<1, 64, 0, stream>>>(part, stats);

    fuse_z<<<4096, 256, 0, stream>>>(gbuf, yb, stats, gnw, gnb, zb);

    // proj -> out (fp32)
    gemm_proj<<<dim3(kC / 128, 4096 / 128), 256, 0, stream>>>(zb, wprojb, out, kC, kC);
}

// Round 12
// 123.162 us; speedup vs baseline: 1.1287x; 1.1287x over previous
//
#include <hip/hip_runtime.h>

typedef __attribute__((ext_vector_type(8))) short bf16x8;
typedef __attribute__((ext_vector_type(4))) float f32x4;
typedef __attribute__((ext_vector_type(16))) float f32x16;
typedef __attribute__((ext_vector_type(2))) unsigned short u16x2;
typedef __attribute__((ext_vector_type(4))) unsigned short u16x4;
typedef __attribute__((ext_vector_type(2))) unsigned int u32x2;

static constexpr int kB = 2;
static constexpr int kT = 2048;
static constexpr int kC = 1024;
static constexpr int kH = 16;
static constexpr int kD = 64;
static constexpr int kNC = 16;  // chunks of 128

__device__ inline unsigned short f2bf(float f) {
    unsigned int u = __float_as_uint(f);
    u += 0x7FFFu + ((u >> 16) & 1u);
    return (unsigned short)(u >> 16);
}
__device__ inline float bf2f(unsigned short u) {
    return __uint_as_float(((unsigned int)u) << 16);
}

#define GLDS16(g, s)                                                            \
    __builtin_amdgcn_global_load_lds(                                           \
        (const __attribute__((address_space(1))) unsigned int*)(g),             \
        (__attribute__((address_space(3))) unsigned int*)(s), 16, 0, 0)

// ---------------- merged f32 -> bf16 convert (x | w_qkv | w_gated | w_proj) -----
// outputs are contiguous bf16 at ws base; segment boundaries all %4 == 0.
__global__ __launch_bounds__(256) void cvt_all(const float* __restrict__ x,
                                               const float* __restrict__ wq,
                                               const float* __restrict__ wg,
                                               const float* __restrict__ wp,
                                               unsigned short* __restrict__ out) {
    int i = (blockIdx.x * 256 + threadIdx.x) * 4;
    if (i >= 9437184) return;
    const float* src;
    int rel;
    if (i < 4194304) { src = x;  rel = i; }
    else if (i < 7340032) { src = wq; rel = i - 4194304; }
    else if (i < 8388608) { src = wg; rel = i - 7340032; }
    else { src = wp; rel = i - 8388608; }
    float4 v = *(const float4*)(src + rel);
    u16x4 o;
    o[0] = f2bf(v.x); o[1] = f2bf(v.y); o[2] = f2bf(v.z); o[3] = f2bf(v.w);
    *(u16x4*)(out + i) = o;
}

// ---------------- RoPE tables + decay LUTs in one launch ----------------
__global__ __launch_bounds__(256) void make_tables(float2* __restrict__ qtab,
                                                   float2* __restrict__ ktab,
                                                   float* __restrict__ decq,
                                                   float* __restrict__ deck) {
    int idx = blockIdx.x * 256 + threadIdx.x;
    if (idx < kT * 32) {
        int t = idx >> 5, i = idx & 31;
        float half = 2.0f * (float)i;
        float inv_freq = powf(10000.0f, -half / 64.0f);
        float fr = (float)t * inv_freq;
        float sv = (half + 0.4f * 64.0f) / (1.4f * 64.0f);
        float p = ((float)t - 1024.0f) / 512.0f;
        float scl = powf(sv, p);
        float c = cosf(fr), s = sinf(fr);
        qtab[idx] = make_float2(c * scl, s * scl);
        ktab[idx] = make_float2(c / scl, s / scl);
    }
    if (idx < kH * 128) {
        int h = idx >> 7, tt = idx & 127;
        float log2g = log2f(1.0f - exp2f(-5.0f - (float)h));
        decq[idx] = 0.125f * exp2f(log2g * (float)tt);
        deck[idx] = exp2f(-log2g * (float)tt);
    }
}

// ---------------- mega input GEMM: C = xb @ [wq;wk;wv;wg]^T (M4096,N4096,K1024) --
// tile 128x128, 4 waves, single-buffer (r9-proven, byte-exact epilogues).
__global__ __launch_bounds__(256) void gemm_qkvg(const unsigned short* __restrict__ A,
                                                 const unsigned short* __restrict__ Bm,
                                                 unsigned short* __restrict__ qb,
                                                 unsigned short* __restrict__ kbuf,
                                                 unsigned short* __restrict__ vtb,
                                                 unsigned short* __restrict__ gbuf) {
    constexpr int K = 1024;
    __shared__ __align__(16) unsigned short Al[128 * 64];
    __shared__ __align__(16) unsigned short Bl[128 * 64];
    char* ab = (char*)Al;
    char* bb = (char*)Bl;
    const int tid = threadIdx.x;
    const int l = tid & 63, w = tid >> 6;
    const int wr = w >> 1, wc = w & 1;
    const int tm = blockIdx.y * 128, tn = blockIdx.x * 128;
    const int ri = l >> 3;
    const int su = (l & 7) ^ (ri & 7);

    f32x4 zero4 = {0.0f, 0.0f, 0.0f, 0.0f};
    f32x4 acc[4][4];
#pragma unroll
    for (int m = 0; m < 4; m++)
#pragma unroll
        for (int n = 0; n < 4; n++) acc[m][n] = zero4;

    for (int kt = 0; kt < K; kt += 64) {
#pragma unroll
        for (int c = w; c < 32; c += 4) {
            if (c < 16) {
                const unsigned short* src = A + (size_t)(tm + c * 8 + ri) * K + kt + su * 8;
                GLDS16(src, ab + c * 1024);
            } else {
                int cb = c - 16;
                const unsigned short* src = Bm + (size_t)(tn + cb * 8 + ri) * K + kt + su * 8;
                GLDS16(src, bb + cb * 1024);
            }
        }
        __syncthreads();
#pragma unroll
        for (int ks = 0; ks < 2; ks++) {
            bf16x8 af[4], bfr[4];
            int kbyte = ks * 64 + (l >> 4) * 16;
#pragma unroll
            for (int m = 0; m < 4; m++) {
                int row = wr * 64 + m * 16 + (l & 15);
                af[m] = *(const bf16x8*)(ab + row * 128 + (kbyte ^ ((row & 7) << 4)));
            }
#pragma unroll
            for (int n = 0; n < 4; n++) {
                int row = wc * 64 + n * 16 + (l & 15);
                bfr[n] = *(const bf16x8*)(bb + row * 128 + (kbyte ^ ((row & 7) << 4)));
            }
#pragma unroll
            for (int m = 0; m < 4; m++)
#pragma unroll
                for (int n = 0; n < 4; n++)
                    acc[m][n] = __builtin_amdgcn_mfma_f32_16x16x32_bf16(af[m], bfr[n], acc[m][n], 0, 0, 0);
        }
        __syncthreads();
    }

    if (tn < 2048) {
        // q or k: plain bf16 (B,H,T,D) rows, u32-packed pair stores
        const bool isq = (tn < 1024);
        unsigned short* dst = isq ? qb : kbuf;
        const int colbase = isq ? tn : (tn - 1024);
#pragma unroll
        for (int n = 0; n < 4; n++) {
            int col = colbase + wc * 64 + n * 16 + (l & 15);
            int h = col >> 6;
            int d = col & 63;
#pragma unroll
            for (int m = 0; m < 4; m++) {
#pragma unroll
                for (int r = 0; r < 4; r++) {
                    int row = tm + wr * 64 + m * 16 + (l >> 4) * 4 + r;
                    int b = row >> 11, t = row & 2047;
                    unsigned int ub = f2bf(acc[m][n][r]);
                    unsigned int pb = (unsigned int)__shfl_xor((int)ub, 1);
                    if (!(l & 1)) {
                        unsigned int packed = (ub & 0xFFFFu) | (pb << 16);
                        *(unsigned int*)(dst + ((size_t)(b * 16 + h) * 2048 + t) * 64 + d) = packed;
                    }
                }
            }
        }
    } else if (tn < 3072) {
        // v: transposed bf16 write (B, Cv, T), u16x4 = 4 consecutive t
#pragma unroll
        for (int m = 0; m < 4; m++)
#pragma unroll
            for (int n = 0; n < 4; n++) {
                int col2 = (tn - 2048) + wc * 64 + n * 16 + (l & 15);
                int rowb = tm + wr * 64 + m * 16 + (l >> 4) * 4;
                int b = rowb >> 11, t = rowb & 2047;
                u16x4 o;
#pragma unroll
                for (int r = 0; r < 4; r++) o[r] = f2bf(acc[m][n][r]);
                *(u16x4*)(vtb + ((size_t)(b * 1024 + col2)) * 2048 + t) = o;
            }
    } else {
        // gated: silu -> bf16 (r9 scalar stores — byte-exact revert)
#pragma unroll
        for (int m = 0; m < 4; m++)
#pragma unroll
            for (int n = 0; n < 4; n++)
#pragma unroll
                for (int r = 0; r < 4; r++) {
                    int row = tm + wr * 64 + m * 16 + (l >> 4) * 4 + r;
                    int col3 = (tn - 3072) + wc * 64 + n * 16 + (l & 15);
                    float v = acc[m][n][r];
                    float sv2 = v / (1.0f + expf(-v));
                    gbuf[(size_t)row * 1024 + col3] = f2bf(sv2);
                }
    }
}

// ---------------- rope_qkt: in-place RoPE+decay on qb,kbuf rows; also emit K^T ----
__global__ __launch_bounds__(256) void rope_qkt(unsigned short* __restrict__ qb,
                                                unsigned short* __restrict__ kbuf,
                                                unsigned short* __restrict__ ktb,
                                                const float2* __restrict__ qtab,
                                                const float2* __restrict__ ktab,
                                                const float* __restrict__ decq,
                                                const float* __restrict__ deck) {
    __shared__ unsigned short tile[64][72];
    const int bh = blockIdx.x;
    const int tt = blockIdx.y * 64;
    const int h = bh & 15;
    const int tl = threadIdx.x >> 2;
    const int du = (threadIdx.x & 3) * 16;
    const int t = tt + tl;
    const float dq = decq[h * 128 + (t & 127)];
    const float dk = deck[h * 128 + (t & 127)];

    {
        unsigned short* qrow = qb + ((size_t)bh * kT + t) * kD + du;
        bf16x8 a0 = *(const bf16x8*)(qrow);
        bf16x8 a1 = *(const bf16x8*)(qrow + 8);
        bf16x8 o0, o1;
#pragma unroll
        for (int j = 0; j < 4; ++j) {
            float2 cs = qtab[t * 32 + (du >> 1) + j];
            float x0 = bf2f((unsigned short)a0[2 * j]);
            float x1 = bf2f((unsigned short)a0[2 * j + 1]);
            o0[2 * j] = (short)f2bf((x0 * cs.x - x1 * cs.y) * dq);
            o0[2 * j + 1] = (short)f2bf((x1 * cs.x + x0 * cs.y) * dq);
            float2 cs2 = qtab[t * 32 + (du >> 1) + 4 + j];
            float y0 = bf2f((unsigned short)a1[2 * j]);
            float y1 = bf2f((unsigned short)a1[2 * j + 1]);
            o1[2 * j] = (short)f2bf((y0 * cs2.x - y1 * cs2.y) * dq);
            o1[2 * j + 1] = (short)f2bf((y1 * cs2.x + y0 * cs2.y) * dq);
        }
        *(bf16x8*)(qrow) = o0;
        *(bf16x8*)(qrow + 8) = o1;
    }
    {
        unsigned short* krow = kbuf + ((size_t)bh * kT + t) * kD + du;
        bf16x8 a0 = *(const bf16x8*)(krow);
        bf16x8 a1 = *(const bf16x8*)(krow + 8);
        bf16x8 o0, o1;
#pragma unroll
        for (int j = 0; j < 4; ++j) {
            float2 cs = ktab[t * 32 + (du >> 1) + j];
            float x0 = bf2f((unsigned short)a0[2 * j]);
            float x1 = bf2f((unsigned short)a0[2 * j + 1]);
            o0[2 * j] = (short)f2bf((x0 * cs.x - x1 * cs.y) * dk);
            o0[2 * j + 1] = (short)f2bf((x1 * cs.x + x0 * cs.y) * dk);
            float2 cs2 = ktab[t * 32 + (du >> 1) + 4 + j];
            float y0 = bf2f((unsigned short)a1[2 * j]);
            float y1 = bf2f((unsigned short)a1[2 * j + 1]);
            o1[2 * j] = (short)f2bf((y0 * cs2.x - y1 * cs2.y) * dk);
            o1[2 * j + 1] = (short)f2bf((y1 * cs2.x + y0 * cs2.y) * dk);
        }
        *(bf16x8*)(krow) = o0;
        *(bf16x8*)(krow + 8) = o1;
#pragma unroll
        for (int e = 0; e < 8; ++e) {
            tile[tl][du + e] = (unsigned short)o0[e];
            tile[tl][du + 8 + e] = (unsigned short)o1[e];
        }
    }
    __syncthreads();
    {
        int dd = threadIdx.x >> 2;
        int tb2 = (threadIdx.x & 3) * 16;
        bf16x8 o0, o1;
#pragma unroll
        for (int e = 0; e < 8; ++e) {
            o0[e] = (short)tile[tb2 + e][dd];
            o1[e] = (short)tile[tb2 + 8 + e][dd];
        }
        unsigned short* drow = ktb + ((size_t)bh * kD + dd) * kT + tt + tb2;
        *(bf16x8*)(drow) = o0;
        *(bf16x8*)(drow + 8) = o1;
    }
}

// ---------------- chunk_m: Mt[bh][c] = g^128 * (V_c^T K~_c) as M^T[d2][d1], bf16 ----
__global__ __launch_bounds__(256) void chunk_m(const unsigned short* __restrict__ ktb,
                                               const unsigned short* __restrict__ vtb,
                                               unsigned short* __restrict__ Mt) {
    __shared__ __align__(16) unsigned short Ktl[64 * 128];
    __shared__ __align__(16) unsigned short Vtl[64 * 128];
    const int tid = threadIdx.x, l = tid & 63, w = tid >> 6;
    const int bh = blockIdx.x, c = blockIdx.y, h = bh & 15;
    const int ql = l & 31, hi5 = l >> 5;
    char* kp = (char*)Ktl;
    char* vp = (char*)Vtl;
#pragma unroll
    for (int j = 0; j < 4; ++j) {
        int ch = w * 4 + j;
        int row = ch * 4 + (l >> 4);
        int u = (l & 15) ^ (row & 15);
        GLDS16(ktb + ((size_t)bh * kD + row) * kT + c * 128 + u * 8, kp + ch * 1024);
        GLDS16(vtb + ((size_t)bh * kD + row) * kT + c * 128 + u * 8, vp + ch * 1024);
    }
    __syncthreads();
    const int iw = w >> 1, jw = w & 1;
    f32x16 acc;
#pragma unroll
    for (int r = 0; r < 16; ++r) acc[r] = 0.0f;
#pragma unroll
    for (int sk = 0; sk < 8; ++sk) {
        int rowa = iw * 32 + ql;
        int rowb = jw * 32 + ql;
        bf16x8 av = *(const bf16x8*)(vp + rowa * 256 + 16 * ((2 * sk + hi5) ^ (rowa & 15)));
        bf16x8 bk = *(const bf16x8*)(kp + rowb * 256 + 16 * ((2 * sk + hi5) ^ (rowb & 15)));
        acc = __builtin_amdgcn_mfma_f32_32x32x16_bf16(av, bk, acc, 0, 0, 0);
    }
    float log2g = log2f(1.0f - exp2f(-5.0f - (float)h));
    float gC = exp2f(128.0f * log2g);
    unsigned short* mo = Mt + ((size_t)(bh * kNC + c)) * 4096;
#pragma unroll
    for (int r = 0; r < 16; ++r) {
        int row = iw * 32 + (r & 3) + 8 * (r >> 2) + 4 * hi5;
        int col = jw * 32 + ql;
        mo[row * 64 + col] = f2bf(acc[r] * gC);
    }
}

// ---------------- chunk_states (serial Horner per bh, 32 blocks) ----------------
__global__ __launch_bounds__(256) void chunk_states(const unsigned short* __restrict__ Mt,
                                                    unsigned short* __restrict__ St) {
    const int bh = blockIdx.x, h = bh & 15;
    const int tid = threadIdx.x;
    float log2g = log2f(1.0f - exp2f(-5.0f - (float)h));
    float gC = exp2f(128.0f * log2g);
    float state[16];
#pragma unroll
    for (int e = 0; e < 16; ++e) state[e] = 0.0f;
    for (int c = 0; c < kNC; ++c) {
        unsigned short* so = St + ((size_t)(bh * kNC + c)) * 4096;
        const unsigned short* m = Mt + ((size_t)(bh * kNC + c)) * 4096;
#pragma unroll
        for (int k = 0; k < 4; ++k) {
            u16x4 o;
#pragma unroll
            for (int e = 0; e < 4; ++e) o[e] = f2bf(state[k * 4 + e]);
            *(u16x4*)(so + (k * 256 + tid) * 4) = o;
            u16x4 v = *(const u16x4*)(m + (k * 256 + tid) * 4);
#pragma unroll
            for (int e = 0; e < 4; ++e)
                state[k * 4 + e] = state[k * 4 + e] * gC + bf2f(v[e]);
        }
    }
}

// ---------------- chunk_attn: y_c = mask(Q~K~^T) V + Q~ S_c (y bf16) + GN partial --
__global__ __launch_bounds__(512) void chunk_attn(const unsigned short* __restrict__ qb,
                                                  const unsigned short* __restrict__ kb,
                                                  const unsigned short* __restrict__ vtb,
                                                  const unsigned short* __restrict__ St,
                                                  unsigned short* __restrict__ yb,
                                                  float* __restrict__ part) {
    __shared__ __align__(16) unsigned short Kt[128 * 64];
    __shared__ __align__(16) unsigned short Vt[64 * 128];
    __shared__ __align__(16) unsigned short Ss[64 * 64];
    __shared__ __align__(16) unsigned short Pl[8 * 32 * 64];
    __shared__ float red[16];
    const int tid = threadIdx.x, l = tid & 63, w = tid >> 6;
    const int bh = blockIdx.x, c = blockIdx.y;
    const int qw = w >> 1, dw = w & 1;
    const int ql = l & 31, hi5 = l >> 5;
    char* kp = (char*)Kt;
    char* vp = (char*)Vt;
    char* sp = (char*)Ss;
    char* pw = (char*)Pl + w * 4096;

#pragma unroll
    for (int j = 0; j < 2; ++j) {
        int ch = w * 2 + j;
        int row = ch * 8 + (l >> 3);
        int u = (l & 7) ^ (row & 7);
        GLDS16(kb + ((size_t)bh * kT + c * 128 + row) * kD + u * 8, kp + ch * 1024);
    }
#pragma unroll
    for (int j = 0; j < 2; ++j) {
        int ch = w * 2 + j;
        int row = ch * 4 + (l >> 4);
        int u = (l & 15) ^ (row & 15);
        GLDS16(vtb + ((size_t)bh * kD + row) * kT + c * 128 + u * 8, vp + ch * 1024);
    }
    {
        int row = w * 8 + (l >> 3);
        int u = (l & 7) ^ (row & 7);
        GLDS16(St + ((size_t)(bh * kNC + c)) * 4096 + row * 64 + u * 8, sp + w * 1024);
    }
    bf16x8 aq[4];
    {
        const unsigned short* qrow = qb + ((size_t)bh * kT + c * 128 + qw * 32 + ql) * kD + hi5 * 8;
#pragma unroll
        for (int dk = 0; dk < 4; ++dk) aq[dk] = *(const bf16x8*)(qrow + dk * 16);
    }
    __syncthreads();

    f32x16 acc;
#pragma unroll
    for (int r = 0; r < 16; ++r) acc[r] = 0.0f;
    const int qidx = qw * 32 + ql;

#pragma unroll
    for (int p = 0; p < 2; ++p) {
        f32x16 sA, sB;
#pragma unroll
        for (int r = 0; r < 16; ++r) { sA[r] = 0.0f; sB[r] = 0.0f; }
#pragma unroll
        for (int dk = 0; dk < 4; ++dk) {
            int rowa = (2 * p) * 32 + ql;
            int rowb = (2 * p + 1) * 32 + ql;
            bf16x8 ka = *(const bf16x8*)(kp + rowa * 128 + 16 * ((2 * dk + hi5) ^ (rowa & 7)));
            bf16x8 kb2 = *(const bf16x8*)(kp + rowb * 128 + 16 * ((2 * dk + hi5) ^ (rowb & 7)));
            sA = __builtin_amdgcn_mfma_f32_32x32x16_bf16(ka, aq[dk], sA, 0, 0, 0);
            sB = __builtin_amdgcn_mfma_f32_32x32x16_bf16(kb2, aq[dk], sB, 0, 0, 0);
        }
#pragma unroll
        for (int sb2 = 0; sb2 < 2; ++sb2) {
            int sbase = (2 * p + sb2) * 32 + 4 * hi5;
#pragma unroll
            for (int m = 0; m < 4; ++m) {
                float v0, v1, v2, v3;
                {
                    int s0i = sbase + 8 * m;
                    float x0 = sb2 ? sB[4 * m + 0] : sA[4 * m + 0];
                    float x1 = sb2 ? sB[4 * m + 1] : sA[4 * m + 1];
                    float x2 = sb2 ? sB[4 * m + 2] : sA[4 * m + 2];
                    float x3 = sb2 ? sB[4 * m + 3] : sA[4 * m + 3];
                    v0 = (qidx >= s0i + 0) ? x0 : 0.0f;
                    v1 = (qidx >= s0i + 1) ? x1 : 0.0f;
                    v2 = (qidx >= s0i + 2) ? x2 : 0.0f;
                    v3 = (qidx >= s0i + 3) ? x3 : 0.0f;
                }
                unsigned int lo, hi;
                asm("v_cvt_pk_bf16_f32 %0, %1, %2" : "=v"(lo) : "v"(v0), "v"(v1));
                asm("v_cvt_pk_bf16_f32 %0, %1, %2" : "=v"(hi) : "v"(v2), "v"(v3));
                u32x2 pr; pr[0] = lo; pr[1] = hi;
                *(u32x2*)(pw + ql * 128 + (((sb2 * 4 + m) * 16) ^ ((ql & 7) << 4)) + hi5 * 8) = pr;
            }
        }
#pragma unroll
        for (int kki = 0; kki < 4; ++kki) {
            bf16x8 ap = *(const bf16x8*)(pw + ql * 128 + 16 * ((2 * kki + hi5) ^ (ql & 7)));
            int rowv = dw * 32 + ql;
            bf16x8 bv = *(const bf16x8*)(vp + rowv * 256 + 16 * ((2 * (4 * p + kki) + hi5) ^ (rowv & 15)));
            acc = __builtin_amdgcn_mfma_f32_32x32x16_bf16(ap, bv, acc, 0, 0, 0);
        }
    }
#pragma unroll
    for (int dk = 0; dk < 4; ++dk) {
        int rows = dw * 32 + ql;
        bf16x8 bs = *(const bf16x8*)(sp + rows * 128 + 16 * ((2 * dk + hi5) ^ (rows & 7)));
        acc = __builtin_amdgcn_mfma_f32_32x32x16_bf16(aq[dk], bs, acc, 0, 0, 0);
    }
    float s = 0.0f, s2 = 0.0f;
#pragma unroll
    for (int r = 0; r < 16; ++r) {
        int row = c * 128 + qw * 32 + (r & 3) + 8 * (r >> 2) + 4 * hi5;
        int col = dw * 32 + ql;
        unsigned short ub = f2bf(acc[r]);
        yb[((size_t)bh * kT + row) * kD + col] = ub;
        float f = bf2f(ub);
        s += f; s2 += f * f;
    }
#pragma unroll
    for (int o = 32; o > 0; o >>= 1) {
        s += __shfl_down(s, o);
        s2 += __shfl_down(s2, o);
    }
    if (l == 0) { red[w * 2] = s; red[w * 2 + 1] = s2; }
    __syncthreads();
    if (tid == 0) {
        float S = 0.0f, S2 = 0.0f;
#pragma unroll
        for (int i = 0; i < 8; i++) { S += red[2 * i]; S2 += red[2 * i + 1]; }
        part[((size_t)bh * kNC + c) * 2] = S;
        part[((size_t)bh * kNC + c) * 2 + 1] = S2;
    }
}

__global__ __launch_bounds__(64) void gn_fin(const float* __restrict__ part,
                                             float* __restrict__ stats) {
    int bh = threadIdx.x;
    if (bh >= kB * kH) return;
    float S = 0.0f, S2 = 0.0f;
#pragma unroll
    for (int i = 0; i < kNC; i++) {
        S += part[(bh * kNC + i) * 2];
        S2 += part[(bh * kNC + i) * 2 + 1];
    }
    const float inv = 1.0f / (float)(kT * kD);
    float mean = S * inv;
    float var = S2 * inv - mean * mean;
    stats[2 * bh] = mean;
    stats[2 * bh + 1] = rsqrtf(var + 1e-5f);
}

// ---------------- proj GEMM: tile 128x64 (2 blocks/CU), fp32 out ----------------
__global__ __launch_bounds__(256) void gemm_proj(const unsigned short* __restrict__ A,
                                                 const unsigned short* __restrict__ Bm,
                                                 float* __restrict__ Cf,
                                                 int N, int K) {
    __shared__ __align__(16) unsigned short Al[128 * 64];
    __shared__ __align__(16) unsigned short Bl[64 * 64];
    char* ab = (char*)Al;
    char* bb = (char*)Bl;
    const int tid = threadIdx.x;
    const int l = tid & 63, w = tid >> 6;
    const int wr = w >> 1, wc = w & 1;
    const int tm = blockIdx.y * 128, tn = blockIdx.x * 64;
    const int ri = l >> 3;
    const int su = (l & 7) ^ (ri & 7);

    f32x4 zero4 = {0.0f, 0.0f, 0.0f, 0.0f};
    f32x4 acc[4][2];
#pragma unroll
    for (int m = 0; m < 4; m++)
#pragma unroll
        for (int n = 0; n < 2; n++) acc[m][n] = zero4;

    for (int kt = 0; kt < K; kt += 64) {
#pragma unroll
        for (int c = w; c < 24; c += 4) {
            if (c < 16) {
                const unsigned short* src = A + (size_t)(tm + c * 8 + ri) * K + kt + su * 8;
                GLDS16(src, ab + c * 1024);
            } else {
                int cb = c - 16;
                const unsigned short* src = Bm + (size_t)(tn + cb * 8 + ri) * K + kt + su * 8;
                GLDS16(src, bb + cb * 1024);
            }
        }
        __syncthreads();
#pragma unroll
        for (int ks = 0; ks < 2; ks++) {
            bf16x8 af[4], bfr[2];
            int kbyte = ks * 64 + (l >> 4) * 16;
#pragma unroll
            for (int m = 0; m < 4; m++) {
                int row = wr * 64 + m * 16 + (l & 15);
                af[m] = *(const bf16x8*)(ab + row * 128 + (kbyte ^ ((row & 7) << 4)));
            }
#pragma unroll
            for (int n = 0; n < 2; n++) {
                int row = wc * 32 + n * 16 + (l & 15);
                bfr[n] = *(const bf16x8*)(bb + row * 128 + (kbyte ^ ((row & 7) << 4)));
            }
#pragma unroll
            for (int m = 0; m < 4; m++)
#pragma unroll
                for (int n = 0; n < 2; n++)
                    acc[m][n] = __builtin_amdgcn_mfma_f32_16x16x32_bf16(af[m], bfr[n], acc[m][n], 0, 0, 0);
        }
        __syncthreads();
    }
#pragma unroll
    for (int m = 0; m < 4; m++)
#pragma unroll
        for (int n = 0; n < 2; n++)
#pragma unroll
            for (int r = 0; r < 4; r++) {
                int row = tm + wr * 64 + m * 16 + (l >> 4) * 4 + r;
                int col = tn + wc * 32 + n * 16 + (l & 15);
                Cf[(size_t)row * N + col] = acc[m][n][r];
            }
}

// ---------------- z = bf16( gsilu * ((y - mean)*rstd*gw + gb) ) ----------------
__global__ __launch_bounds__(256) void fuse_z(const unsigned short* __restrict__ gb,
                                              const unsigned short* __restrict__ yb,
                                              const float* __restrict__ stats,
                                              const float* __restrict__ gnw,
                                              const float* __restrict__ gnb,
                                              unsigned short* __restrict__ z) {
    int idx = blockIdx.x * 256 + threadIdx.x;  // (B*T*C)/4
    int row = idx >> 8;
    int c = (idx & 255) << 2;
    int b = row >> 11, t = row & 2047;
    int h = c >> 6, d = c & 63;
    int bh = b * kH + h;
    u16x4 gv = *(const u16x4*)(gb + (size_t)row * kC + c);
    u16x4 yv = *(const u16x4*)(yb + (((size_t)bh * kT) + t) * kD + d);
    float mean = stats[2 * bh], rstd = stats[2 * bh + 1];
    float4 wv = *(const float4*)(gnw + c);
    float4 bv = *(const float4*)(gnb + c);
    u16x4 o;
    o[0] = f2bf(bf2f(gv[0]) * ((bf2f(yv[0]) - mean) * rstd * wv.x + bv.x));
    o[1] = f2bf(bf2f(gv[1]) * ((bf2f(yv[1]) - mean) * rstd * wv.y + bv.y));
    o[2] = f2bf(bf2f(gv[2]) * ((bf2f(yv[2]) - mean) * rstd * wv.z + bv.z));
    o[3] = f2bf(bf2f(gv[3]) * ((bf2f(yv[3]) - mean) * rstd * wv.w + bv.w));
    *(u16x4*)(z + (size_t)row * kC + c) = o;
}

extern "C" void kernel_launch(void* const* d_in, const int* in_sizes, int n_in,
                              void* d_out, int out_size, void* d_ws, size_t ws_size,
                              hipStream_t stream) {
    const float* x = (const float*)d_in[0];
    const float* w_qkv = (const float*)d_in[1];
    const float* w_gated = (const float*)d_in[2];
    const float* w_proj = (const float*)d_in[3];
    const float* gnw = (const float*)d_in[4];
    const float* gnb = (const float*)d_in[5];
    float* out = (float*)d_out;
    char* ws = (char*)d_ws;

    unsigned short* xb      = (unsigned short*)(ws + 0);         // 8 MB
    unsigned short* wqkvb   = (unsigned short*)(ws + 8388608);   // 6 MB
    unsigned short* wprojb  = (unsigned short*)(ws + 16777216);  // 2 MB
    unsigned short* qb      = (unsigned short*)(ws + 18874368);  // 8 MB (B,H,T,D)
    unsigned short* kbuf    = (unsigned short*)(ws + 27262976);  // 8 MB (B,H,T,D)
    unsigned short* vtb     = (unsigned short*)(ws + 35651584);  // 8 MB (B,H,D,T)
    unsigned short* zb      = (unsigned short*)(ws + 44040192);  // 8 MB
    float* part  = (float*)(ws + 44040192);                      // 4 KB in zb (dead before fuse_z)
    float* stats = (float*)(ws + 52428800);                      // 256 B
    float2* qtab = (float2*)(ws + 52429056);                     // 512 KB
    float2* ktab = (float2*)(ws + 52953344);                     // 512 KB
    float*  decq = (float*)(ws + 53477632);                      // 8 KB
    float*  deck = (float*)(ws + 53485824);                      // 8 KB
    unsigned short* Mt  = (unsigned short*)(ws + 52429056);      // 4 MB (overlays tables)
    unsigned short* St  = (unsigned short*)(ws + 56623360);      // 4 MB
    unsigned short* yb  = (unsigned short*)(ws + 60817664);      // 8 MB
    unsigned short* gbuf= (unsigned short*)(ws + 69206272);      // 8 MB
    unsigned short* ktb = (unsigned short*)(ws + 77594880);      // 8 MB -> ends 85983232

    // merged convert: x | w_qkv | w_gated | w_proj -> contiguous bf16 at ws base
    cvt_all<<<9216, 256, 0, stream>>>(x, w_qkv, w_gated, w_proj, xb);
    make_tables<<<256, 256, 0, stream>>>(qtab, ktab, decq, deck);

    // mega GEMM: q->qb, k->kbuf (plain rows), v->vtb (transposed), gated->gbuf (silu)
    gemm_qkvg<<<dim3(32, 32), 256, 0, stream>>>(xb, wqkvb, qb, kbuf, vtb, gbuf);

    // in-place rope on qb/kbuf + emit K^T
    rope_qkt<<<dim3(kB * kH, kT / 64), 256, 0, stream>>>(qb, kbuf, ktb, qtab, ktab, decq, deck);

    // chunked retention (bh fastest -> XCD = bh%8)
    chunk_m<<<dim3(kB * kH, kNC), 256, 0, stream>>>(ktb, vtb, Mt);
    chunk_states<<<kB * kH, 256, 0, stream>>>(Mt, St);
    chunk_attn<<<dim3(kB * kH, kNC), 512, 0, stream>>>(qb, kbuf, vtb, St, yb, part);

    gn_fin<<<1, 64, 0, stream>>>(part, stats);

    fuse_z<<<4096, 256, 0, stream>>>(gbuf, yb, stats, gnw, gnb, zb);

    // proj -> out (fp32), 512 blocks = 2/CU
    gemm_proj<<<dim3(kC / 64, 4096 / 128), 256, 0, stream>>>(zb, wprojb, out, kC, kC);
}

// Round 13
// 120.370 us; speedup vs baseline: 1.1548x; 1.0232x over previous
//
#include <hip/hip_runtime.h>

typedef __attribute__((ext_vector_type(8))) short bf16x8;
typedef __attribute__((ext_vector_type(4))) float f32x4;
typedef __attribute__((ext_vector_type(16))) float f32x16;
typedef __attribute__((ext_vector_type(2))) unsigned short u16x2;
typedef __attribute__((ext_vector_type(4))) unsigned short u16x4;
typedef __attribute__((ext_vector_type(8))) unsigned short u16x8;
typedef __attribute__((ext_vector_type(2))) unsigned int u32x2;

static constexpr int kB = 2;
static constexpr int kT = 2048;
static constexpr int kC = 1024;
static constexpr int kH = 16;
static constexpr int kD = 64;
static constexpr int kNC = 16;  // chunks of 128

__device__ inline unsigned short f2bf(float f) {
    unsigned int u = __float_as_uint(f);
    u += 0x7FFFu + ((u >> 16) & 1u);
    return (unsigned short)(u >> 16);
}
__device__ inline float bf2f(unsigned short u) {
    return __uint_as_float(((unsigned int)u) << 16);
}

#define GLDS16(g, s)                                                            \
    __builtin_amdgcn_global_load_lds(                                           \
        (const __attribute__((address_space(1))) unsigned int*)(g),             \
        (__attribute__((address_space(3))) unsigned int*)(s), 16, 0, 0)

// ------- merged f32->bf16 convert (x | w_qkv | w_gated | w_proj) + tables -------
__global__ __launch_bounds__(256) void cvt_all(const float* __restrict__ x,
                                               const float* __restrict__ wq,
                                               const float* __restrict__ wg,
                                               const float* __restrict__ wp,
                                               unsigned short* __restrict__ out,
                                               float2* __restrict__ qtab,
                                               float2* __restrict__ ktab,
                                               float* __restrict__ decq,
                                               float* __restrict__ deck) {
    int idx = blockIdx.x * 256 + threadIdx.x;
    // rope/decay tables (first 64K threads)
    if (idx < kT * 32) {
        int t = idx >> 5, i = idx & 31;
        float half = 2.0f * (float)i;
        float inv_freq = powf(10000.0f, -half / 64.0f);
        float fr = (float)t * inv_freq;
        float sv = (half + 0.4f * 64.0f) / (1.4f * 64.0f);
        float p = ((float)t - 1024.0f) / 512.0f;
        float scl = powf(sv, p);
        float c = cosf(fr), s = sinf(fr);
        qtab[idx] = make_float2(c * scl, s * scl);
        ktab[idx] = make_float2(c / scl, s / scl);
    }
    if (idx < kH * 128) {
        int h = idx >> 7, tt = idx & 127;
        float log2g = log2f(1.0f - exp2f(-5.0f - (float)h));
        decq[idx] = 0.125f * exp2f(log2g * (float)tt);
        deck[idx] = exp2f(-log2g * (float)tt);
    }
    int i = idx * 4;
    if (i >= 9437184) return;
    const float* src;
    int rel;
    if (i < 4194304) { src = x;  rel = i; }
    else if (i < 7340032) { src = wq; rel = i - 4194304; }
    else if (i < 8388608) { src = wg; rel = i - 7340032; }
    else { src = wp; rel = i - 8388608; }
    float4 v = *(const float4*)(src + rel);
    u16x4 o;
    o[0] = f2bf(v.x); o[1] = f2bf(v.y); o[2] = f2bf(v.z); o[3] = f2bf(v.w);
    *(u16x4*)(out + i) = o;
}

// ---------------- mega input GEMM: C = xb @ [wq;wk;wv;wg]^T (M4096,N4096,K1024) --
// tile 128x128, 4 waves, single-buffer (r9-proven, byte-exact epilogues).
__global__ __launch_bounds__(256) void gemm_qkvg(const unsigned short* __restrict__ A,
                                                 const unsigned short* __restrict__ Bm,
                                                 unsigned short* __restrict__ qb,
                                                 unsigned short* __restrict__ kbuf,
                                                 unsigned short* __restrict__ vtb,
                                                 unsigned short* __restrict__ gbuf) {
    constexpr int K = 1024;
    __shared__ __align__(16) unsigned short Al[128 * 64];
    __shared__ __align__(16) unsigned short Bl[128 * 64];
    char* ab = (char*)Al;
    char* bb = (char*)Bl;
    const int tid = threadIdx.x;
    const int l = tid & 63, w = tid >> 6;
    const int wr = w >> 1, wc = w & 1;
    const int tm = blockIdx.y * 128, tn = blockIdx.x * 128;
    const int ri = l >> 3;
    const int su = (l & 7) ^ (ri & 7);

    f32x4 zero4 = {0.0f, 0.0f, 0.0f, 0.0f};
    f32x4 acc[4][4];
#pragma unroll
    for (int m = 0; m < 4; m++)
#pragma unroll
        for (int n = 0; n < 4; n++) acc[m][n] = zero4;

    for (int kt = 0; kt < K; kt += 64) {
#pragma unroll
        for (int c = w; c < 32; c += 4) {
            if (c < 16) {
                const unsigned short* src = A + (size_t)(tm + c * 8 + ri) * K + kt + su * 8;
                GLDS16(src, ab + c * 1024);
            } else {
                int cb = c - 16;
                const unsigned short* src = Bm + (size_t)(tn + cb * 8 + ri) * K + kt + su * 8;
                GLDS16(src, bb + cb * 1024);
            }
        }
        __syncthreads();
#pragma unroll
        for (int ks = 0; ks < 2; ks++) {
            bf16x8 af[4], bfr[4];
            int kbyte = ks * 64 + (l >> 4) * 16;
#pragma unroll
            for (int m = 0; m < 4; m++) {
                int row = wr * 64 + m * 16 + (l & 15);
                af[m] = *(const bf16x8*)(ab + row * 128 + (kbyte ^ ((row & 7) << 4)));
            }
#pragma unroll
            for (int n = 0; n < 4; n++) {
                int row = wc * 64 + n * 16 + (l & 15);
                bfr[n] = *(const bf16x8*)(bb + row * 128 + (kbyte ^ ((row & 7) << 4)));
            }
#pragma unroll
            for (int m = 0; m < 4; m++)
#pragma unroll
                for (int n = 0; n < 4; n++)
                    acc[m][n] = __builtin_amdgcn_mfma_f32_16x16x32_bf16(af[m], bfr[n], acc[m][n], 0, 0, 0);
        }
        __syncthreads();
    }

    if (tn < 2048) {
        // q or k: plain bf16 (B,H,T,D) rows, u32-packed pair stores
        const bool isq = (tn < 1024);
        unsigned short* dst = isq ? qb : kbuf;
        const int colbase = isq ? tn : (tn - 1024);
#pragma unroll
        for (int n = 0; n < 4; n++) {
            int col = colbase + wc * 64 + n * 16 + (l & 15);
            int h = col >> 6;
            int d = col & 63;
#pragma unroll
            for (int m = 0; m < 4; m++) {
#pragma unroll
                for (int r = 0; r < 4; r++) {
                    int row = tm + wr * 64 + m * 16 + (l >> 4) * 4 + r;
                    int b = row >> 11, t = row & 2047;
                    unsigned int ub = f2bf(acc[m][n][r]);
                    unsigned int pb = (unsigned int)__shfl_xor((int)ub, 1);
                    if (!(l & 1)) {
                        unsigned int packed = (ub & 0xFFFFu) | (pb << 16);
                        *(unsigned int*)(dst + ((size_t)(b * 16 + h) * 2048 + t) * 64 + d) = packed;
                    }
                }
            }
        }
    } else if (tn < 3072) {
        // v: transposed bf16 write (B, Cv, T), u16x4 = 4 consecutive t
#pragma unroll
        for (int m = 0; m < 4; m++)
#pragma unroll
            for (int n = 0; n < 4; n++) {
                int col2 = (tn - 2048) + wc * 64 + n * 16 + (l & 15);
                int rowb = tm + wr * 64 + m * 16 + (l >> 4) * 4;
                int b = rowb >> 11, t = rowb & 2047;
                u16x4 o;
#pragma unroll
                for (int r = 0; r < 4; r++) o[r] = f2bf(acc[m][n][r]);
                *(u16x4*)(vtb + ((size_t)(b * 1024 + col2)) * 2048 + t) = o;
            }
    } else {
        // gated: silu -> bf16 (scalar stores)
#pragma unroll
        for (int m = 0; m < 4; m++)
#pragma unroll
            for (int n = 0; n < 4; n++)
#pragma unroll
                for (int r = 0; r < 4; r++) {
                    int row = tm + wr * 64 + m * 16 + (l >> 4) * 4 + r;
                    int col3 = (tn - 3072) + wc * 64 + n * 16 + (l & 15);
                    float v = acc[m][n][r];
                    float sv2 = v / (1.0f + expf(-v));
                    gbuf[(size_t)row * 1024 + col3] = f2bf(sv2);
                }
    }
}

// ---------------- rope_qkt: in-place RoPE+decay on qb,kbuf rows; also emit K^T ----
__global__ __launch_bounds__(256) void rope_qkt(unsigned short* __restrict__ qb,
                                                unsigned short* __restrict__ kbuf,
                                                unsigned short* __restrict__ ktb,
                                                const float2* __restrict__ qtab,
                                                const float2* __restrict__ ktab,
                                                const float* __restrict__ decq,
                                                const float* __restrict__ deck) {
    __shared__ unsigned short tile[64][72];
    const int bh = blockIdx.x;
    const int tt = blockIdx.y * 64;
    const int h = bh & 15;
    const int tl = threadIdx.x >> 2;
    const int du = (threadIdx.x & 3) * 16;
    const int t = tt + tl;
    const float dq = decq[h * 128 + (t & 127)];
    const float dk = deck[h * 128 + (t & 127)];

    {
        unsigned short* qrow = qb + ((size_t)bh * kT + t) * kD + du;
        bf16x8 a0 = *(const bf16x8*)(qrow);
        bf16x8 a1 = *(const bf16x8*)(qrow + 8);
        bf16x8 o0, o1;
#pragma unroll
        for (int j = 0; j < 4; ++j) {
            float2 cs = qtab[t * 32 + (du >> 1) + j];
            float x0 = bf2f((unsigned short)a0[2 * j]);
            float x1 = bf2f((unsigned short)a0[2 * j + 1]);
            o0[2 * j] = (short)f2bf((x0 * cs.x - x1 * cs.y) * dq);
            o0[2 * j + 1] = (short)f2bf((x1 * cs.x + x0 * cs.y) * dq);
            float2 cs2 = qtab[t * 32 + (du >> 1) + 4 + j];
            float y0 = bf2f((unsigned short)a1[2 * j]);
            float y1 = bf2f((unsigned short)a1[2 * j + 1]);
            o1[2 * j] = (short)f2bf((y0 * cs2.x - y1 * cs2.y) * dq);
            o1[2 * j + 1] = (short)f2bf((y1 * cs2.x + y0 * cs2.y) * dq);
        }
        *(bf16x8*)(qrow) = o0;
        *(bf16x8*)(qrow + 8) = o1;
    }
    {
        unsigned short* krow = kbuf + ((size_t)bh * kT + t) * kD + du;
        bf16x8 a0 = *(const bf16x8*)(krow);
        bf16x8 a1 = *(const bf16x8*)(krow + 8);
        bf16x8 o0, o1;
#pragma unroll
        for (int j = 0; j < 4; ++j) {
            float2 cs = ktab[t * 32 + (du >> 1) + j];
            float x0 = bf2f((unsigned short)a0[2 * j]);
            float x1 = bf2f((unsigned short)a0[2 * j + 1]);
            o0[2 * j] = (short)f2bf((x0 * cs.x - x1 * cs.y) * dk);
            o0[2 * j + 1] = (short)f2bf((x1 * cs.x + x0 * cs.y) * dk);
            float2 cs2 = ktab[t * 32 + (du >> 1) + 4 + j];
            float y0 = bf2f((unsigned short)a1[2 * j]);
            float y1 = bf2f((unsigned short)a1[2 * j + 1]);
            o1[2 * j] = (short)f2bf((y0 * cs2.x - y1 * cs2.y) * dk);
            o1[2 * j + 1] = (short)f2bf((y1 * cs2.x + y0 * cs2.y) * dk);
        }
        *(bf16x8*)(krow) = o0;
        *(bf16x8*)(krow + 8) = o1;
#pragma unroll
        for (int e = 0; e < 8; ++e) {
            tile[tl][du + e] = (unsigned short)o0[e];
            tile[tl][du + 8 + e] = (unsigned short)o1[e];
        }
    }
    __syncthreads();
    {
        int dd = threadIdx.x >> 2;
        int tb2 = (threadIdx.x & 3) * 16;
        bf16x8 o0, o1;
#pragma unroll
        for (int e = 0; e < 8; ++e) {
            o0[e] = (short)tile[tb2 + e][dd];
            o1[e] = (short)tile[tb2 + 8 + e][dd];
        }
        unsigned short* drow = ktb + ((size_t)bh * kD + dd) * kT + tt + tb2;
        *(bf16x8*)(drow) = o0;
        *(bf16x8*)(drow + 8) = o1;
    }
}

// ---------------- chunk_m: Mt[bh][c] = g^128 * (V_c^T K~_c) as M^T[d2][d1], bf16 ----
__global__ __launch_bounds__(256) void chunk_m(const unsigned short* __restrict__ ktb,
                                               const unsigned short* __restrict__ vtb,
                                               unsigned short* __restrict__ Mt) {
    __shared__ __align__(16) unsigned short Ktl[64 * 128];
    __shared__ __align__(16) unsigned short Vtl[64 * 128];
    const int tid = threadIdx.x, l = tid & 63, w = tid >> 6;
    const int bh = blockIdx.x, c = blockIdx.y, h = bh & 15;
    const int ql = l & 31, hi5 = l >> 5;
    char* kp = (char*)Ktl;
    char* vp = (char*)Vtl;
#pragma unroll
    for (int j = 0; j < 4; ++j) {
        int ch = w * 4 + j;
        int row = ch * 4 + (l >> 4);
        int u = (l & 15) ^ (row & 15);
        GLDS16(ktb + ((size_t)bh * kD + row) * kT + c * 128 + u * 8, kp + ch * 1024);
        GLDS16(vtb + ((size_t)bh * kD + row) * kT + c * 128 + u * 8, vp + ch * 1024);
    }
    __syncthreads();
    const int iw = w >> 1, jw = w & 1;
    f32x16 acc;
#pragma unroll
    for (int r = 0; r < 16; ++r) acc[r] = 0.0f;
#pragma unroll
    for (int sk = 0; sk < 8; ++sk) {
        int rowa = iw * 32 + ql;
        int rowb = jw * 32 + ql;
        bf16x8 av = *(const bf16x8*)(vp + rowa * 256 + 16 * ((2 * sk + hi5) ^ (rowa & 15)));
        bf16x8 bk = *(const bf16x8*)(kp + rowb * 256 + 16 * ((2 * sk + hi5) ^ (rowb & 15)));
        acc = __builtin_amdgcn_mfma_f32_32x32x16_bf16(av, bk, acc, 0, 0, 0);
    }
    float log2g = log2f(1.0f - exp2f(-5.0f - (float)h));
    float gC = exp2f(128.0f * log2g);
    unsigned short* mo = Mt + ((size_t)(bh * kNC + c)) * 4096;
#pragma unroll
    for (int r = 0; r < 16; ++r) {
        int row = iw * 32 + (r & 3) + 8 * (r >> 2) + 4 * hi5;
        int col = jw * 32 + ql;
        mo[row * 64 + col] = f2bf(acc[r] * gC);
    }
}

// ---------------- chunk_states (serial Horner per bh, 32 blocks) ----------------
__global__ __launch_bounds__(256) void chunk_states(const unsigned short* __restrict__ Mt,
                                                    unsigned short* __restrict__ St) {
    const int bh = blockIdx.x, h = bh & 15;
    const int tid = threadIdx.x;
    float log2g = log2f(1.0f - exp2f(-5.0f - (float)h));
    float gC = exp2f(128.0f * log2g);
    float state[16];
#pragma unroll
    for (int e = 0; e < 16; ++e) state[e] = 0.0f;
    for (int c = 0; c < kNC; ++c) {
        unsigned short* so = St + ((size_t)(bh * kNC + c)) * 4096;
        const unsigned short* m = Mt + ((size_t)(bh * kNC + c)) * 4096;
#pragma unroll
        for (int k = 0; k < 4; ++k) {
            u16x4 o;
#pragma unroll
            for (int e = 0; e < 4; ++e) o[e] = f2bf(state[k * 4 + e]);
            *(u16x4*)(so + (k * 256 + tid) * 4) = o;
            u16x4 v = *(const u16x4*)(m + (k * 256 + tid) * 4);
#pragma unroll
            for (int e = 0; e < 4; ++e)
                state[k * 4 + e] = state[k * 4 + e] * gC + bf2f(v[e]);
        }
    }
}

// ---------------- chunk_attn: y_c = mask(Q~K~^T) V + Q~ S_c (y bf16) + GN partial --
__global__ __launch_bounds__(512) void chunk_attn(const unsigned short* __restrict__ qb,
                                                  const unsigned short* __restrict__ kb,
                                                  const unsigned short* __restrict__ vtb,
                                                  const unsigned short* __restrict__ St,
                                                  unsigned short* __restrict__ yb,
                                                  float* __restrict__ part) {
    __shared__ __align__(16) unsigned short Kt[128 * 64];
    __shared__ __align__(16) unsigned short Vt[64 * 128];
    __shared__ __align__(16) unsigned short Ss[64 * 64];
    __shared__ __align__(16) unsigned short Pl[8 * 32 * 64];
    __shared__ float red[16];
    const int tid = threadIdx.x, l = tid & 63, w = tid >> 6;
    const int bh = blockIdx.x, c = blockIdx.y;
    const int qw = w >> 1, dw = w & 1;
    const int ql = l & 31, hi5 = l >> 5;
    char* kp = (char*)Kt;
    char* vp = (char*)Vt;
    char* sp = (char*)Ss;
    char* pw = (char*)Pl + w * 4096;

#pragma unroll
    for (int j = 0; j < 2; ++j) {
        int ch = w * 2 + j;
        int row = ch * 8 + (l >> 3);
        int u = (l & 7) ^ (row & 7);
        GLDS16(kb + ((size_t)bh * kT + c * 128 + row) * kD + u * 8, kp + ch * 1024);
    }
#pragma unroll
    for (int j = 0; j < 2; ++j) {
        int ch = w * 2 + j;
        int row = ch * 4 + (l >> 4);
        int u = (l & 15) ^ (row & 15);
        GLDS16(vtb + ((size_t)bh * kD + row) * kT + c * 128 + u * 8, vp + ch * 1024);
    }
    {
        int row = w * 8 + (l >> 3);
        int u = (l & 7) ^ (row & 7);
        GLDS16(St + ((size_t)(bh * kNC + c)) * 4096 + row * 64 + u * 8, sp + w * 1024);
    }
    bf16x8 aq[4];
    {
        const unsigned short* qrow = qb + ((size_t)bh * kT + c * 128 + qw * 32 + ql) * kD + hi5 * 8;
#pragma unroll
        for (int dk = 0; dk < 4; ++dk) aq[dk] = *(const bf16x8*)(qrow + dk * 16);
    }
    __syncthreads();

    f32x16 acc;
#pragma unroll
    for (int r = 0; r < 16; ++r) acc[r] = 0.0f;
    const int qidx = qw * 32 + ql;

#pragma unroll
    for (int p = 0; p < 2; ++p) {
        f32x16 sA, sB;
#pragma unroll
        for (int r = 0; r < 16; ++r) { sA[r] = 0.0f; sB[r] = 0.0f; }
#pragma unroll
        for (int dk = 0; dk < 4; ++dk) {
            int rowa = (2 * p) * 32 + ql;
            int rowb = (2 * p + 1) * 32 + ql;
            bf16x8 ka = *(const bf16x8*)(kp + rowa * 128 + 16 * ((2 * dk + hi5) ^ (rowa & 7)));
            bf16x8 kb2 = *(const bf16x8*)(kp + rowb * 128 + 16 * ((2 * dk + hi5) ^ (rowb & 7)));
            sA = __builtin_amdgcn_mfma_f32_32x32x16_bf16(ka, aq[dk], sA, 0, 0, 0);
            sB = __builtin_amdgcn_mfma_f32_32x32x16_bf16(kb2, aq[dk], sB, 0, 0, 0);
        }
#pragma unroll
        for (int sb2 = 0; sb2 < 2; ++sb2) {
            int sbase = (2 * p + sb2) * 32 + 4 * hi5;
#pragma unroll
            for (int m = 0; m < 4; ++m) {
                float v0, v1, v2, v3;
                {
                    int s0i = sbase + 8 * m;
                    float x0 = sb2 ? sB[4 * m + 0] : sA[4 * m + 0];
                    float x1 = sb2 ? sB[4 * m + 1] : sA[4 * m + 1];
                    float x2 = sb2 ? sB[4 * m + 2] : sA[4 * m + 2];
                    float x3 = sb2 ? sB[4 * m + 3] : sA[4 * m + 3];
                    v0 = (qidx >= s0i + 0) ? x0 : 0.0f;
                    v1 = (qidx >= s0i + 1) ? x1 : 0.0f;
                    v2 = (qidx >= s0i + 2) ? x2 : 0.0f;
                    v3 = (qidx >= s0i + 3) ? x3 : 0.0f;
                }
                unsigned int lo, hi;
                asm("v_cvt_pk_bf16_f32 %0, %1, %2" : "=v"(lo) : "v"(v0), "v"(v1));
                asm("v_cvt_pk_bf16_f32 %0, %1, %2" : "=v"(hi) : "v"(v2), "v"(v3));
                u32x2 pr; pr[0] = lo; pr[1] = hi;
                *(u32x2*)(pw + ql * 128 + (((sb2 * 4 + m) * 16) ^ ((ql & 7) << 4)) + hi5 * 8) = pr;
            }
        }
#pragma unroll
        for (int kki = 0; kki < 4; ++kki) {
            bf16x8 ap = *(const bf16x8*)(pw + ql * 128 + 16 * ((2 * kki + hi5) ^ (ql & 7)));
            int rowv = dw * 32 + ql;
            bf16x8 bv = *(const bf16x8*)(vp + rowv * 256 + 16 * ((2 * (4 * p + kki) + hi5) ^ (rowv & 15)));
            acc = __builtin_amdgcn_mfma_f32_32x32x16_bf16(ap, bv, acc, 0, 0, 0);
        }
    }
#pragma unroll
    for (int dk = 0; dk < 4; ++dk) {
        int rows = dw * 32 + ql;
        bf16x8 bs = *(const bf16x8*)(sp + rows * 128 + 16 * ((2 * dk + hi5) ^ (rows & 7)));
        acc = __builtin_amdgcn_mfma_f32_32x32x16_bf16(aq[dk], bs, acc, 0, 0, 0);
    }
    float s = 0.0f, s2 = 0.0f;
#pragma unroll
    for (int r = 0; r < 16; ++r) {
        int row = c * 128 + qw * 32 + (r & 3) + 8 * (r >> 2) + 4 * hi5;
        int col = dw * 32 + ql;
        unsigned short ub = f2bf(acc[r]);
        yb[((size_t)bh * kT + row) * kD + col] = ub;
        float f = bf2f(ub);
        s += f; s2 += f * f;
    }
#pragma unroll
    for (int o = 32; o > 0; o >>= 1) {
        s += __shfl_down(s, o);
        s2 += __shfl_down(s2, o);
    }
    if (l == 0) { red[w * 2] = s; red[w * 2 + 1] = s2; }
    __syncthreads();
    if (tid == 0) {
        float S = 0.0f, S2 = 0.0f;
#pragma unroll
        for (int i = 0; i < 8; i++) { S += red[2 * i]; S2 += red[2 * i + 1]; }
        part[((size_t)bh * kNC + c) * 2] = S;
        part[((size_t)bh * kNC + c) * 2 + 1] = S2;
    }
}

__global__ __launch_bounds__(64) void gn_fin(const float* __restrict__ part,
                                             float* __restrict__ stats) {
    int bh = threadIdx.x;
    if (bh >= kB * kH) return;
    float S = 0.0f, S2 = 0.0f;
#pragma unroll
    for (int i = 0; i < kNC; i++) {
        S += part[(bh * kNC + i) * 2];
        S2 += part[(bh * kNC + i) * 2 + 1];
    }
    const float inv = 1.0f / (float)(kT * kD);
    float mean = S * inv;
    float var = S2 * inv - mean * mean;
    stats[2 * bh] = mean;
    stats[2 * bh + 1] = rsqrtf(var + 1e-5f);
}

// ---------------- proj GEMM: tile 128x64 (2 blocks/CU), fp32 out ----------------
__global__ __launch_bounds__(256) void gemm_proj(const unsigned short* __restrict__ A,
                                                 const unsigned short* __restrict__ Bm,
                                                 float* __restrict__ Cf,
                                                 int N, int K) {
    __shared__ __align__(16) unsigned short Al[128 * 64];
    __shared__ __align__(16) unsigned short Bl[64 * 64];
    char* ab = (char*)Al;
    char* bb = (char*)Bl;
    const int tid = threadIdx.x;
    const int l = tid & 63, w = tid >> 6;
    const int wr = w >> 1, wc = w & 1;
    const int tm = blockIdx.y * 128, tn = blockIdx.x * 64;
    const int ri = l >> 3;
    const int su = (l & 7) ^ (ri & 7);

    f32x4 zero4 = {0.0f, 0.0f, 0.0f, 0.0f};
    f32x4 acc[4][2];
#pragma unroll
    for (int m = 0; m < 4; m++)
#pragma unroll
        for (int n = 0; n < 2; n++) acc[m][n] = zero4;

    for (int kt = 0; kt < K; kt += 64) {
#pragma unroll
        for (int c = w; c < 24; c += 4) {
            if (c < 16) {
                const unsigned short* src = A + (size_t)(tm + c * 8 + ri) * K + kt + su * 8;
                GLDS16(src, ab + c * 1024);
            } else {
                int cb = c - 16;
                const unsigned short* src = Bm + (size_t)(tn + cb * 8 + ri) * K + kt + su * 8;
                GLDS16(src, bb + cb * 1024);
            }
        }
        __syncthreads();
#pragma unroll
        for (int ks = 0; ks < 2; ks++) {
            bf16x8 af[4], bfr[2];
            int kbyte = ks * 64 + (l >> 4) * 16;
#pragma unroll
            for (int m = 0; m < 4; m++) {
                int row = wr * 64 + m * 16 + (l & 15);
                af[m] = *(const bf16x8*)(ab + row * 128 + (kbyte ^ ((row & 7) << 4)));
            }
#pragma unroll
            for (int n = 0; n < 2; n++) {
                int row = wc * 32 + n * 16 + (l & 15);
                bfr[n] = *(const bf16x8*)(bb + row * 128 + (kbyte ^ ((row & 7) << 4)));
            }
#pragma unroll
            for (int m = 0; m < 4; m++)
#pragma unroll
                for (int n = 0; n < 2; n++)
                    acc[m][n] = __builtin_amdgcn_mfma_f32_16x16x32_bf16(af[m], bfr[n], acc[m][n], 0, 0, 0);
        }
        __syncthreads();
    }
#pragma unroll
    for (int m = 0; m < 4; m++)
#pragma unroll
        for (int n = 0; n < 2; n++)
#pragma unroll
            for (int r = 0; r < 4; r++) {
                int row = tm + wr * 64 + m * 16 + (l >> 4) * 4 + r;
                int col = tn + wc * 32 + n * 16 + (l & 15);
                Cf[(size_t)row * N + col] = acc[m][n][r];
            }
}

// ---------------- z = bf16( gsilu * ((y - mean)*rstd*gw + gb) ), 16B/thread ------
__global__ __launch_bounds__(256) void fuse_z(const unsigned short* __restrict__ gb,
                                              const unsigned short* __restrict__ yb,
                                              const float* __restrict__ stats,
                                              const float* __restrict__ gnw,
                                              const float* __restrict__ gnb,
                                              unsigned short* __restrict__ z) {
    int idx = blockIdx.x * 256 + threadIdx.x;  // (B*T*C)/8
    int row = idx >> 7;
    int c = (idx & 127) << 3;
    int b = row >> 11, t = row & 2047;
    int h = c >> 6, d = c & 63;
    int bh = b * kH + h;
    u16x8 gv = *(const u16x8*)(gb + (size_t)row * kC + c);
    u16x8 yv = *(const u16x8*)(yb + (((size_t)bh * kT) + t) * kD + d);
    float mean = stats[2 * bh], rstd = stats[2 * bh + 1];
    float4 wv0 = *(const float4*)(gnw + c);
    float4 wv1 = *(const float4*)(gnw + c + 4);
    float4 bv0 = *(const float4*)(gnb + c);
    float4 bv1 = *(const float4*)(gnb + c + 4);
    float wvs[8] = {wv0.x, wv0.y, wv0.z, wv0.w, wv1.x, wv1.y, wv1.z, wv1.w};
    float bvs[8] = {bv0.x, bv0.y, bv0.z, bv0.w, bv1.x, bv1.y, bv1.z, bv1.w};
    u16x8 o;
#pragma unroll
    for (int e = 0; e < 8; ++e)
        o[e] = f2bf(bf2f(gv[e]) * ((bf2f(yv[e]) - mean) * rstd * wvs[e] + bvs[e]));
    *(u16x8*)(z + (size_t)row * kC + c) = o;
}

extern "C" void kernel_launch(void* const* d_in, const int* in_sizes, int n_in,
                              void* d_out, int out_size, void* d_ws, size_t ws_size,
                              hipStream_t stream) {
    const float* x = (const float*)d_in[0];
    const float* w_qkv = (const float*)d_in[1];
    const float* w_gated = (const float*)d_in[2];
    const float* w_proj = (const float*)d_in[3];
    const float* gnw = (const float*)d_in[4];
    const float* gnb = (const float*)d_in[5];
    float* out = (float*)d_out;
    char* ws = (char*)d_ws;

    unsigned short* xb      = (unsigned short*)(ws + 0);         // 8 MB
    unsigned short* wqkvb   = (unsigned short*)(ws + 8388608);   // 6 MB
    unsigned short* wprojb  = (unsigned short*)(ws + 16777216);  // 2 MB
    unsigned short* qb      = (unsigned short*)(ws + 18874368);  // 8 MB (B,H,T,D)
    unsigned short* kbuf    = (unsigned short*)(ws + 27262976);  // 8 MB (B,H,T,D)
    unsigned short* vtb     = (unsigned short*)(ws + 35651584);  // 8 MB (B,H,D,T)
    unsigned short* zb      = (unsigned short*)(ws + 44040192);  // 8 MB
    float* part  = (float*)(ws + 44040192);                      // 4 KB in zb (dead before fuse_z)
    float* stats = (float*)(ws + 52428800);                      // 256 B
    float2* qtab = (float2*)(ws + 52429056);                     // 512 KB
    float2* ktab = (float2*)(ws + 52953344);                     // 512 KB
    float*  decq = (float*)(ws + 53477632);                      // 8 KB
    float*  deck = (float*)(ws + 53485824);                      // 8 KB
    unsigned short* Mt  = (unsigned short*)(ws + 52429056);      // 4 MB (overlays tables)
    unsigned short* St  = (unsigned short*)(ws + 56623360);      // 4 MB
    unsigned short* yb  = (unsigned short*)(ws + 60817664);      // 8 MB
    unsigned short* gbuf= (unsigned short*)(ws + 69206272);      // 8 MB
    unsigned short* ktb = (unsigned short*)(ws + 77594880);      // 8 MB -> ends 85983232

    // merged convert + table generation (one launch)
    cvt_all<<<9216, 256, 0, stream>>>(x, w_qkv, w_gated, w_proj, xb,
                                      qtab, ktab, decq, deck);

    // mega GEMM: q->qb, k->kbuf (plain rows), v->vtb (transposed), gated->gbuf (silu)
    gemm_qkvg<<<dim3(32, 32), 256, 0, stream>>>(xb, wqkvb, qb, kbuf, vtb, gbuf);

    // in-place rope on qb/kbuf + emit K^T
    rope_qkt<<<dim3(kB * kH, kT / 64), 256, 0, stream>>>(qb, kbuf, ktb, qtab, ktab, decq, deck);

    // chunked retention (bh fastest -> XCD = bh%8)
    chunk_m<<<dim3(kB * kH, kNC), 256, 0, stream>>>(ktb, vtb, Mt);
    chunk_states<<<kB * kH, 256, 0, stream>>>(Mt, St);
    chunk_attn<<<dim3(kB * kH, kNC), 512, 0, stream>>>(qb, kbuf, vtb, St, yb, part);

    gn_fin<<<1, 64, 0, stream>>>(part, stats);

    fuse_z<<<2048, 256, 0, stream>>>(gbuf, yb, stats, gnw, gnb, zb);

    // proj -> out (fp32), 512 blocks = 2/CU
    gemm_proj<<<dim3(kC / 64, 4096 / 128), 256, 0, stream>>>(zb, wprojb, out, kC, kC);
}